// Round 5
// baseline (1085.047 us; speedup 1.0000x reference)
//
#include <hip/hip_runtime.h>
#include <cstdint>
#include <cstddef>

#define N_NODESC 100000
#define N_EDGESC 400000
#define N_GRAPHSC 2048
#define F_INC 78
#define HEADS1C 10
#define D1C 78           // per-head out dim, layer 1
#define F1C 780          // HEADS1C * D1C
#define ZP 960           // padded z row: 10 heads x 96
#define OUT2C 128
#define E_TOTC (N_EDGESC + N_NODESC)   // 500000 edges incl. self-loops

typedef unsigned short ushort_t;
typedef __attribute__((ext_vector_type(8))) short short8;
typedef __attribute__((ext_vector_type(4))) float f32x4;
typedef __attribute__((ext_vector_type(4))) unsigned int uint4v;
union U4S8 { uint4v u; short8 s; };

static __device__ __forceinline__ float lrelu(float x){ return x > 0.f ? x : 0.2f*x; }

// bf16 helpers (round-to-nearest-even)
static __device__ __forceinline__ unsigned short f2bf(float f){
  unsigned int u = __float_as_uint(f);
  unsigned int r = (u + 0x7fffu + ((u >> 16) & 1u)) >> 16;
  return (unsigned short)r;
}
static __device__ __forceinline__ float bf2f(unsigned short h){
  return __uint_as_float(((unsigned int)h) << 16);
}

// ---------------- CSR build ----------------
__global__ void k_deg(const int* __restrict__ ei, int* __restrict__ deg){
  int e = blockIdx.x*256 + threadIdx.x;
  if (e >= E_TOTC) return;
  int dst = (e < N_EDGESC) ? ei[N_EDGESC + e] : (e - N_EDGESC);
  atomicAdd(&deg[dst], 1);
}

__global__ __launch_bounds__(1024) void k_scan1(const int* __restrict__ deg,
                                                int* __restrict__ rowptr,
                                                int* __restrict__ bsum){
  __shared__ int s[1024];
  int t = threadIdx.x, i = blockIdx.x*1024 + t;
  int v = (i < N_NODESC) ? deg[i] : 0;
  s[t] = v; __syncthreads();
  for (int d = 1; d < 1024; d <<= 1){
    int xv = (t >= d) ? s[t-d] : 0;
    __syncthreads();
    s[t] += xv;
    __syncthreads();
  }
  if (i < N_NODESC) rowptr[i+1] = s[t];
  if (t == 1023) bsum[blockIdx.x] = s[t];
}

__global__ void k_scan2(int* __restrict__ bsum, int* __restrict__ rowptr, int nb){
  if (threadIdx.x == 0 && blockIdx.x == 0){
    int run = 0;
    for (int b = 0; b < nb; b++){ int v = bsum[b]; bsum[b] = run; run += v; }
    rowptr[0] = 0;
  }
}

__global__ __launch_bounds__(1024) void k_scan3(int* __restrict__ rowptr,
                                                const int* __restrict__ bsum){
  int i = blockIdx.x*1024 + threadIdx.x;
  if (i < N_NODESC) rowptr[i+1] += bsum[blockIdx.x];
}

__global__ void k_scatter(const int* __restrict__ ei, const int* __restrict__ rowptr,
                          int* __restrict__ cnt, int* __restrict__ esrc){
  int e = blockIdx.x*256 + threadIdx.x;
  if (e >= E_TOTC) return;
  int src, dst;
  if (e < N_EDGESC){ src = ei[e]; dst = ei[N_EDGESC + e]; }
  else { src = dst = e - N_EDGESC; }
  int pos = rowptr[dst] + atomicAdd(&cnt[dst], 1);
  esrc[pos] = src;
}

// ---------------- layer-1 attention logit precompute ----------------
__global__ void k_wa1(const float* __restrict__ W1, const float* __restrict__ a_src1,
                      const float* __restrict__ a_dst1, float* __restrict__ Wa1){
  int i = blockIdx.x*256 + threadIdx.x;
  if (i >= F_INC*2*HEADS1C) return;
  int d = i / (2*HEADS1C), c = i % (2*HEADS1C);
  const float* a = (c < HEADS1C) ? a_src1 : a_dst1;
  int h = (c < HEADS1C) ? c : c - HEADS1C;
  float s = 0.f;
  for (int j = 0; j < D1C; j++) s += W1[d*F1C + h*D1C + j] * a[h*D1C + j];
  Wa1[d*(2*HEADS1C) + c] = s;
}

// att1[n*20 + h] = alpha_src[n,h];  att1[n*20 + 10 + h] = alpha_dst[n,h]
__global__ void k_att1(const float* __restrict__ x, const float* __restrict__ Wa1,
                       float* __restrict__ att1){
  int i = blockIdx.x*256 + threadIdx.x;
  if (i >= N_NODESC*2*HEADS1C) return;
  int n = i / (2*HEADS1C), c = i % (2*HEADS1C);
  const float* xr = x + (size_t)n*F_INC;
  float s = 0.f;
  for (int d = 0; d < F_INC; d++) s += xr[d] * Wa1[d*(2*HEADS1C) + c];
  att1[i] = s;
}

// one wave per node, ONLINE softmax fused: zc[local][h*96+d] = softmax-agg of x
__global__ __launch_bounds__(64) void k_agg1(
    const float* __restrict__ x, const float* __restrict__ att1,
    const int* __restrict__ rowptr, const int* __restrict__ esrc,
    ushort_t* __restrict__ zc, int base){
  __shared__ float xs[F_INC];
  __shared__ float al[HEADS1C];
  __shared__ float cr[HEADS1C];
  int n = base + blockIdx.x;
  int l = threadIdx.x;
  int b = rowptr[n], e = rowptr[n+1];
  float acc[15];
  #pragma unroll
  for (int k = 0; k < 15; k++) acc[k] = 0.f;
  int hk[15], dk[15];
  #pragma unroll
  for (int k = 0; k < 15; k++){ int f = l + 64*k; hk[k] = f/96; dk[k] = f%96; }
  float ad = 0.f, m = -1e30f, den = 0.f;
  if (l < HEADS1C) ad = att1[n*20 + 10 + l];
  for (int p = b; p < e; p++){
    int s = esrc[p];
    if (l < 39){
      float2 v = *(const float2*)(x + (size_t)s*F_INC + 2*l);
      xs[2*l] = v.x; xs[2*l+1] = v.y;
    }
    if (l < HEADS1C){
      float ev = lrelu(att1[s*20 + l] + ad);
      float mn = fmaxf(m, ev);
      float c  = expf(m - mn);
      float a  = expf(ev - mn);
      den = den*c + a;
      m = mn;
      al[l] = a; cr[l] = c;
    }
    __syncthreads();
    #pragma unroll
    for (int k = 0; k < 15; k++)
      if (dk[k] < 78) acc[k] = acc[k]*cr[hk[k]] + al[hk[k]]*xs[dk[k]];
    __syncthreads();
  }
  if (l < HEADS1C) al[l] = 1.f/(den + 1e-16f);
  __syncthreads();
  #pragma unroll
  for (int k = 0; k < 15; k++){
    int f = l + 64*k;
    float v = (dk[k] < 78) ? acc[k]*al[hk[k]] : 0.f;
    zc[(size_t)blockIdx.x*ZP + f] = f2bf(v);
  }
}

// ---------------- weight prep (zero-padded bf16) ----------------
__global__ void k_prepW1(const float* __restrict__ W1, ushort_t* __restrict__ W1t){
  // W1t[h][n(80)][k(96)] = bf16(W1[k][h*78+n]) with zero pad
  int i = blockIdx.x*256 + threadIdx.x;
  if (i >= HEADS1C*80*96) return;
  int h = i / (80*96), rem = i % (80*96), n = rem / 96, k = rem % 96;
  float v = (n < D1C && k < F_INC) ? W1[(size_t)k*F1C + h*D1C + n] : 0.f;
  W1t[i] = f2bf(v);
}

// W2p[n(128)][h*96+d] = bf16(W2[h*78+d][n]), zeros for d>=78
__global__ void k_prepW2p(const float* __restrict__ W2, ushort_t* __restrict__ W2p){
  int i = blockIdx.x*256 + threadIdx.x;
  if (i >= OUT2C*ZP) return;
  int n = i / ZP, kk = i % ZP;
  int h = kk / 96, d = kk % 96;
  float v = (d < D1C) ? W2[(size_t)(h*D1C + d)*OUT2C + n] : 0.f;
  W2p[i] = f2bf(v);
}

// generic: Wt[n][k(KB)] = bf16(W[k][n]) zero-padded in k
__global__ void k_prepWt(const float* __restrict__ W, ushort_t* __restrict__ Wt,
                         int Kdim, int Ndim, int KB){
  int i = blockIdx.x*256 + threadIdx.x;
  if (i >= Ndim*KB) return;
  int n = i / KB, k = i % KB;
  float v = (k < Kdim) ? W[(size_t)k*Ndim + n] : 0.f;
  Wt[i] = f2bf(v);
}

__global__ void k_cast_bf(const float* __restrict__ in, ushort_t* __restrict__ o, int n){
  int i = blockIdx.x*256 + threadIdx.x;
  if (i < n) o[i] = f2bf(in[i]);
}

// ---------------- fused layer-1: h2pre = (elu(z @ bdW1 + b1)) @ W2 ----------
// Per block: 64 nodes. Loop heads: stage zc slice -> MFMA -> elu h1 to LDS
// (C-layout -> A-layout) -> MFMA vs W2p slice -> accumulate h2pre in regs.
__global__ __launch_bounds__(256) void k_l1fused(
    const ushort_t* __restrict__ zc,   // [R][960]
    const ushort_t* __restrict__ W1t,  // [10][80][96]
    const float*    __restrict__ b1,   // [780]
    const ushort_t* __restrict__ W2p,  // [128][960]
    ushort_t* __restrict__ h2pre,      // [N][128]
    int R, int base)
{
  __shared__ unsigned int AH[64][52];    // A-tile, then h1-tile (aliased)
  __shared__ unsigned int B1s[80][52];
  __shared__ unsigned int B2s[128][52];
  int m0 = blockIdx.x*64;
  int t = threadIdx.x;
  int w = t >> 6, lane = t & 63, q = lane >> 4, li = lane & 15;
  ushort_t* h1p = (ushort_t*)&AH[0][0];  // [64][104] ushorts
  f32x4 acc2[8];
  #pragma unroll
  for (int i = 0; i < 8; i++) acc2[i] = (f32x4){0.f,0.f,0.f,0.f};

  for (int h = 0; h < HEADS1C; h++){
    // stage A (64x96), B1 (80x96), B2 (128x96)
    for (int i = t; i < 768; i += 256){
      int r = i/12, c = i%12;
      uint4v v = (uint4v){0u,0u,0u,0u};
      if (m0 + r < R)
        v = *(const uint4v*)(zc + (size_t)(m0+r)*ZP + h*96 + c*8);
      *(uint4v*)&AH[r][c*4] = v;
    }
    for (int i = t; i < 960; i += 256){
      int r = i/12, c = i%12;
      *(uint4v*)&B1s[r][c*4] = *(const uint4v*)(W1t + (size_t)h*7680 + r*96 + c*8);
    }
    for (int i = t; i < 1536; i += 256){
      int r = i/12, c = i%12;
      *(uint4v*)&B2s[r][c*4] = *(const uint4v*)(W2p + (size_t)r*ZP + h*96 + c*8);
    }
    __syncthreads();
    // GEMM1: h1 head block (64 x 80)
    f32x4 acc1[5];
    #pragma unroll
    for (int i = 0; i < 5; i++) acc1[i] = (f32x4){0.f,0.f,0.f,0.f};
    #pragma unroll
    for (int kt = 0; kt < 3; kt++){
      U4S8 a; a.u = *(const uint4v*)&AH[w*16 + li][kt*16 + q*4];
      #pragma unroll
      for (int nt = 0; nt < 5; nt++){
        U4S8 b; b.u = *(const uint4v*)&B1s[nt*16 + li][kt*16 + q*4];
        acc1[nt] = __builtin_amdgcn_mfma_f32_16x16x32_bf16(a.s, b.s, acc1[nt], 0,0,0);
      }
    }
    __syncthreads();   // all waves done reading AH as A-tile
    // epilogue1: elu(h1)+bias -> AH as bf16 A-layout
    #pragma unroll
    for (int nt = 0; nt < 5; nt++){
      int col = nt*16 + li;
      float bv = (col < D1C) ? b1[h*D1C + col] : 0.f;
      #pragma unroll
      for (int r = 0; r < 4; r++){
        int row = w*16 + q*4 + r;
        float v = acc1[nt][r] + bv;
        v = (v > 0.f) ? v : expm1f(v);
        if (col >= D1C) v = 0.f;
        h1p[row*104 + col] = f2bf(v);
      }
    }
    // zero pad cols 80..95 (dwords 40..47)
    for (int i = t; i < 512; i += 256){
      int r = i >> 3, dw = 40 + (i & 7);
      AH[r][dw] = 0u;
    }
    __syncthreads();
    // GEMM2: accumulate h2pre tile (64 x 128)
    #pragma unroll
    for (int kt = 0; kt < 3; kt++){
      U4S8 a; a.u = *(const uint4v*)&AH[w*16 + li][kt*16 + q*4];
      #pragma unroll
      for (int nt = 0; nt < 8; nt++){
        U4S8 b; b.u = *(const uint4v*)&B2s[nt*16 + li][kt*16 + q*4];
        acc2[nt] = __builtin_amdgcn_mfma_f32_16x16x32_bf16(a.s, b.s, acc2[nt], 0,0,0);
      }
    }
    __syncthreads();
  }
  // write h2pre
  #pragma unroll
  for (int nt = 0; nt < 8; nt++){
    int col = nt*16 + li;
    #pragma unroll
    for (int r = 0; r < 4; r++){
      int row = m0 + w*16 + q*4 + r;
      if (row < R)
        h2pre[(size_t)(base + row)*OUT2C + col] = f2bf(acc2[nt][r]);
    }
  }
}

// ---------------- MFMA bf16 GEMM (MLP head) ---------------------------------
template<int BN, int NT, int KB, int ACT, bool HASBIAS>
__global__ __launch_bounds__(256) void mfma_gemm(
    const ushort_t* __restrict__ A, const ushort_t* __restrict__ Bt,
    const float* __restrict__ bias, ushort_t* __restrict__ C,
    int M, int N, int K, int lda, int ldc)
{
  __shared__ unsigned int As[64][20];   // 64 rows x 32 bf16 (+pad), 80B stride
  __shared__ unsigned int Bs[BN][20];
  int m0 = blockIdx.x*64;
  int n0 = blockIdx.y*BN;
  int t = threadIdx.x;
  int w = t >> 6, lane = t & 63;
  int q = lane >> 4, li = lane & 15;
  f32x4 acc[NT];
  #pragma unroll
  for (int i = 0; i < NT; i++) acc[i] = (f32x4){0.f,0.f,0.f,0.f};

  int am = t >> 2;           // 0..63
  int ak0 = (t & 3)*8;       // 0,8,16,24
  int gm = m0 + am;

  for (int kt = 0; kt < KB; kt += 32){
    {
      unsigned int u0,u1,u2,u3;
      int gk = kt + ak0;
      if (gm < M && gk + 8 <= K){
        const unsigned int* ap = (const unsigned int*)(A + (size_t)gm*lda + gk);
        u0 = ap[0]; u1 = ap[1]; u2 = ap[2]; u3 = ap[3];
      } else {
        ushort_t tmp[8];
        #pragma unroll
        for (int j = 0; j < 8; j++)
          tmp[j] = (gm < M && gk + j < K) ? A[(size_t)gm*lda + gk + j] : (ushort_t)0;
        u0 = tmp[0] | ((unsigned)tmp[1]<<16);
        u1 = tmp[2] | ((unsigned)tmp[3]<<16);
        u2 = tmp[4] | ((unsigned)tmp[5]<<16);
        u3 = tmp[6] | ((unsigned)tmp[7]<<16);
      }
      int c0 = (t & 3)*4;
      As[am][c0] = u0; As[am][c0+1] = u1; As[am][c0+2] = u2; As[am][c0+3] = u3;
    }
    for (int g = t; g < BN*4; g += 256){
      int n = g >> 2, c0 = (g & 3)*4;
      const unsigned int* bp = (const unsigned int*)(Bt + (size_t)(n0 + n)*KB + kt + c0*2);
      Bs[n][c0] = bp[0]; Bs[n][c0+1] = bp[1]; Bs[n][c0+2] = bp[2]; Bs[n][c0+3] = bp[3];
    }
    __syncthreads();
    U4S8 a; a.u = *(const uint4v*)&As[w*16 + li][q*4];
    #pragma unroll
    for (int nt = 0; nt < NT; nt++){
      U4S8 b; b.u = *(const uint4v*)&Bs[nt*16 + li][q*4];
      acc[nt] = __builtin_amdgcn_mfma_f32_16x16x32_bf16(a.s, b.s, acc[nt], 0, 0, 0);
    }
    __syncthreads();
  }
  #pragma unroll
  for (int nt = 0; nt < NT; nt++){
    int col = n0 + nt*16 + li;
    if (col >= N) continue;
    float bv = HASBIAS ? bias[col] : 0.f;
    #pragma unroll
    for (int r = 0; r < 4; r++){
      int gmr = m0 + w*16 + q*4 + r;
      if (gmr >= M) continue;
      float v = acc[nt][r] + bv;
      if (ACT == 1) v = fmaxf(v, 0.f);
      else if (ACT == 2) v = (v > 0.f) ? v : expm1f(v);
      C[(size_t)gmr*ldc + col] = f2bf(v);
    }
  }
}

// ---------------- layer-2 attention ----------------
__global__ void k_att2(const ushort_t* __restrict__ h2pre,
                       const float* __restrict__ a_src2,
                       const float* __restrict__ a_dst2, float* __restrict__ att2){
  int n = blockIdx.x*4 + (threadIdx.x >> 6);
  int l = threadIdx.x & 63;
  if (n >= N_NODESC) return;
  const ushort_t* r = h2pre + (size_t)n*OUT2C;
  float v0 = bf2f(r[l]), v1 = bf2f(r[64+l]);
  float p0 = v0*a_src2[l] + v1*a_src2[64+l];
  float p1 = v0*a_dst2[l] + v1*a_dst2[64+l];
  #pragma unroll
  for (int off = 32; off; off >>= 1){
    p0 += __shfl_xor(p0, off);
    p1 += __shfl_xor(p1, off);
  }
  if (l == 0){ att2[n*2] = p0; att2[n*2+1] = p1; }
}

__global__ void k_stats2(const float* __restrict__ att2, const int* __restrict__ rowptr,
                         const int* __restrict__ esrc, float* __restrict__ stat2){
  int n = blockIdx.x*256 + threadIdx.x;
  if (n >= N_NODESC) return;
  float ad = att2[n*2+1];
  int b = rowptr[n], e = rowptr[n+1];
  float m = -1e30f;
  for (int p = b; p < e; p++) m = fmaxf(m, lrelu(att2[esrc[p]*2] + ad));
  float den = 0.f;
  for (int p = b; p < e; p++) den += expf(lrelu(att2[esrc[p]*2] + ad) - m);
  stat2[n*2] = m;
  stat2[n*2+1] = 1.f/(den + 1e-16f);
}

__global__ void k_agg2(const ushort_t* __restrict__ h2pre,
                       const float* __restrict__ att2,
                       const float* __restrict__ stat2, const int* __restrict__ rowptr,
                       const int* __restrict__ esrc, const float* __restrict__ b2,
                       const float* __restrict__ w_gate, const float* __restrict__ b_gate,
                       float* __restrict__ h2, float* __restrict__ wnode){
  int n = blockIdx.x*4 + (threadIdx.x >> 6);
  int l = threadIdx.x & 63;
  if (n >= N_NODESC) return;
  float ad = att2[n*2+1], m = stat2[n*2], rd = stat2[n*2+1];
  int b = rowptr[n], e = rowptr[n+1];
  float a0 = 0.f, a1 = 0.f;
  for (int p = b; p < e; p++){
    int s = esrc[p];
    float alpha = expf(lrelu(att2[s*2] + ad) - m) * rd;
    a0 += alpha * bf2f(h2pre[(size_t)s*OUT2C + l]);
    a1 += alpha * bf2f(h2pre[(size_t)s*OUT2C + 64 + l]);
  }
  float v0 = fmaxf(a0 + b2[l], 0.f);
  float v1 = fmaxf(a1 + b2[64+l], 0.f);
  h2[(size_t)n*OUT2C + l] = v0;
  h2[(size_t)n*OUT2C + 64 + l] = v1;
  float p = v0*w_gate[l] + v1*w_gate[64+l];
  #pragma unroll
  for (int off = 32; off; off >>= 1) p += __shfl_xor(p, off);
  if (l == 0) wnode[n] = 1.f/(1.f + expf(-(p + b_gate[0])));
}

// one block per graph: weighted-sum + max readout, bf16 out into xcb[:, 0:256]
__global__ __launch_bounds__(128) void k_readout(const float* __restrict__ h2,
                                                 const float* __restrict__ wnode,
                                                 const int* __restrict__ batch,
                                                 ushort_t* __restrict__ xcb){
  __shared__ int lohi[2];
  int g = blockIdx.x, t = threadIdx.x;
  if (t == 0){
    int lo = 0, hi = N_NODESC;
    while (lo < hi){ int mid = (lo+hi) >> 1; if (batch[mid] < g) lo = mid+1; else hi = mid; }
    lohi[0] = lo;
    int lo2 = lo; hi = N_NODESC;
    while (lo2 < hi){ int mid = (lo2+hi) >> 1; if (batch[mid] < g+1) lo2 = mid+1; else hi = mid; }
    lohi[1] = lo2;
  }
  __syncthreads();
  int lo = lohi[0], hi = lohi[1];
  float sum = 0.f, mx = 0.f;
  for (int n = lo; n < hi; n++){
    float v = h2[(size_t)n*OUT2C + t];
    sum += v * wnode[n];
    mx = fmaxf(mx, v);
  }
  xcb[(size_t)g*512 + t] = f2bf(sum);
  xcb[(size_t)g*512 + 128 + t] = f2bf(mx);
}

__global__ void k_final(const ushort_t* __restrict__ f2b, const float* __restrict__ W_out,
                        const float* __restrict__ b_out, float* __restrict__ out){
  int g = blockIdx.x*4 + (threadIdx.x >> 6);
  int l = threadIdx.x & 63;
  if (g >= N_GRAPHSC) return;
  float s = 0.f;
  #pragma unroll
  for (int k = 0; k < 4; k++) s += bf2f(f2b[(size_t)g*256 + l + 64*k]) * W_out[l + 64*k];
  #pragma unroll
  for (int off = 32; off; off >>= 1) s += __shfl_xor(s, off);
  if (l == 0) out[g] = s + b_out[0];
}

extern "C" void kernel_launch(void* const* d_in, const int* in_sizes, int n_in,
                              void* d_out, int out_size, void* d_ws, size_t ws_size,
                              hipStream_t stream) {
  const float* x      = (const float*)d_in[0];
  const int*   ei     = (const int*)d_in[1];
  const int*   batch  = (const int*)d_in[2];
  const float* target = (const float*)d_in[3];
  const float* W1     = (const float*)d_in[4];
  const float* a_src1 = (const float*)d_in[5];
  const float* a_dst1 = (const float*)d_in[6];
  const float* b1     = (const float*)d_in[7];
  const float* W2     = (const float*)d_in[8];
  const float* a_src2 = (const float*)d_in[9];
  const float* a_dst2 = (const float*)d_in[10];
  const float* b2     = (const float*)d_in[11];
  const float* w_gate = (const float*)d_in[12];
  const float* b_gate = (const float*)d_in[13];
  const float* W_xt   = (const float*)d_in[14];
  const float* b_xt   = (const float*)d_in[15];
  const float* W_fc1  = (const float*)d_in[16];
  const float* b_fc1  = (const float*)d_in[17];
  const float* W_fc2  = (const float*)d_in[18];
  const float* b_fc2  = (const float*)d_in[19];
  const float* W_out  = (const float*)d_in[20];
  const float* b_out  = (const float*)d_in[21];
  float* out = (float*)d_out;

  // ---- adaptive chunking so the carve fits ws_size ----
  const size_t MB = (size_t)1 << 20;
  int C;
  if      (ws_size >= 256*MB) C = 1;   // ~240 MB
  else if (ws_size >= 156*MB) C = 2;   // ~144 MB
  else                        C = 4;   // ~99 MB
  const int R = N_NODESC / C;

  char* p = (char*)d_ws;
  auto carve = [&](size_t bytes) -> char* {
    char* r = p; p += (bytes + 255) & ~(size_t)255; return r;
  };
  int*   deg    = (int*)  carve((size_t)N_NODESC*4);
  int*   rowptr = (int*)  carve((size_t)(N_NODESC+1)*4);
  int*   cnt    = (int*)  carve((size_t)N_NODESC*4);
  int*   esrc   = (int*)  carve((size_t)E_TOTC*4);
  int*   bsum   = (int*)  carve(128*4);
  float* Wa1    = (float*)carve((size_t)F_INC*20*4);
  float* att1   = (float*)carve((size_t)N_NODESC*20*4);
  float* att2   = (float*)carve((size_t)N_NODESC*2*4);
  float* stat2  = (float*)carve((size_t)N_NODESC*2*4);
  float* wnode  = (float*)carve((size_t)N_NODESC*4);
  ushort_t* W1t   = (ushort_t*)carve((size_t)HEADS1C*80*96*2);
  ushort_t* W2p   = (ushort_t*)carve((size_t)OUT2C*ZP*2);
  ushort_t* Wxtt  = (ushort_t*)carve((size_t)256*1280*2);
  ushort_t* Wfc1t = (ushort_t*)carve((size_t)1024*512*2);
  ushort_t* Wfc2t = (ushort_t*)carve((size_t)256*1024*2);
  ushort_t* tb    = (ushort_t*)carve((size_t)N_GRAPHSC*1280*2);
  ushort_t* h2pre = (ushort_t*)carve((size_t)N_NODESC*OUT2C*2);
  ushort_t* xcb   = (ushort_t*)carve((size_t)N_GRAPHSC*512*2);
  ushort_t* f1b   = (ushort_t*)carve((size_t)N_GRAPHSC*1024*2);
  ushort_t* f2b   = (ushort_t*)carve((size_t)N_GRAPHSC*256*2);
  size_t big_bytes = (size_t)R*ZP*2;                    // zc (bf16, padded)
  size_t h2_bytes  = (size_t)N_NODESC*OUT2C*4;          // h2 (fp32)
  char*  BIG = carve(big_bytes > h2_bytes ? big_bytes : h2_bytes);
  ushort_t* zc = (ushort_t*)BIG;
  float* h2 = (float*)BIG;   // overlays zc AFTER all k_l1fused chunks are done

  hipMemsetAsync(deg, 0, (size_t)N_NODESC*4, stream);
  hipMemsetAsync(cnt, 0, (size_t)N_NODESC*4, stream);

  // CSR by destination (self-loops appended)
  k_deg<<<(E_TOTC+255)/256, 256, 0, stream>>>(ei, deg);
  int nb = (N_NODESC + 1023)/1024;
  k_scan1<<<nb, 1024, 0, stream>>>(deg, rowptr, bsum);
  k_scan2<<<1, 64, 0, stream>>>(bsum, rowptr, nb);
  k_scan3<<<nb, 1024, 0, stream>>>(rowptr, bsum);
  k_scatter<<<(E_TOTC+255)/256, 256, 0, stream>>>(ei, rowptr, cnt, esrc);

  // weight prep (bf16, zero-padded) + target cast
  k_prepW1<<<(HEADS1C*80*96+255)/256, 256, 0, stream>>>(W1, W1t);
  k_prepW2p<<<(OUT2C*ZP+255)/256, 256, 0, stream>>>(W2, W2p);
  k_prepWt<<<(256*1280+255)/256, 256, 0, stream>>>(W_xt, Wxtt, 1280, 256, 1280);
  k_prepWt<<<(1024*512+255)/256, 256, 0, stream>>>(W_fc1, Wfc1t, 512, 1024, 512);
  k_prepWt<<<(256*1024+255)/256, 256, 0, stream>>>(W_fc2, Wfc2t, 1024, 256, 1024);
  k_cast_bf<<<((N_GRAPHSC*1280)+255)/256, 256, 0, stream>>>(target, tb, N_GRAPHSC*1280);

  // layer-1 attention logits via folded weights
  k_wa1<<<(F_INC*20+255)/256, 256, 0, stream>>>(W1, a_src1, a_dst1, Wa1);
  k_att1<<<(N_NODESC*20+255)/256, 256, 0, stream>>>(x, Wa1, att1);

  // layer-1 (chunked): fused online-softmax agg -> zc; fused double-GEMM -> h2pre
  for (int c = 0; c < C; c++){
    int base = c*R;
    k_agg1<<<R, 64, 0, stream>>>(x, att1, rowptr, esrc, zc, base);
    k_l1fused<<<(R+63)/64, 256, 0, stream>>>(zc, W1t, b1, W2p, h2pre, R, base);
  }

  // layer-2 attention + aggregation (h2 overlays the dead zc region)
  k_att2<<<(N_NODESC+3)/4, 256, 0, stream>>>(h2pre, a_src2, a_dst2, att2);
  k_stats2<<<(N_NODESC+255)/256, 256, 0, stream>>>(att2, rowptr, esrc, stat2);
  k_agg2<<<(N_NODESC+3)/4, 256, 0, stream>>>(h2pre, att2, stat2, rowptr, esrc,
                                             b2, w_gate, b_gate, h2, wnode);

  // readout (bf16) + MLP head via MFMA
  k_readout<<<N_GRAPHSC, 128, 0, stream>>>(h2, wnode, batch, xcb);
  mfma_gemm<128,8,1280,0,true><<<dim3(N_GRAPHSC/64, 256/128, 1), 256, 0, stream>>>(
      tb, Wxtt, b_xt, xcb + 256, N_GRAPHSC, 256, 1280, 1280, 512);
  mfma_gemm<128,8,512,1,true><<<dim3(N_GRAPHSC/64, 1024/128, 1), 256, 0, stream>>>(
      xcb, Wfc1t, b_fc1, f1b, N_GRAPHSC, 1024, 512, 512, 1024);
  mfma_gemm<128,8,1024,1,true><<<dim3(N_GRAPHSC/64, 256/128, 1), 256, 0, stream>>>(
      f1b, Wfc2t, b_fc2, f2b, N_GRAPHSC, 256, 1024, 1024, 256);
  k_final<<<(N_GRAPHSC+3)/4, 256, 0, stream>>>(f2b, W_out, b_out, out);
}

// Round 6
// 1046.916 us; speedup vs baseline: 1.0364x; 1.0364x over previous
//
#include <hip/hip_runtime.h>
#include <cstdint>
#include <cstddef>

#define N_NODESC 100000
#define N_EDGESC 400000
#define N_GRAPHSC 2048
#define F_INC 78
#define HEADS1C 10
#define D1C 78           // per-head out dim, layer 1
#define F1C 780          // HEADS1C * D1C
#define ZP 960           // padded z row: 10 heads x 96
#define OUT2C 128
#define E_TOTC (N_EDGESC + N_NODESC)   // 500000 edges incl. self-loops

typedef unsigned short ushort_t;
typedef __attribute__((ext_vector_type(8))) short short8;
typedef __attribute__((ext_vector_type(4))) float f32x4;
typedef __attribute__((ext_vector_type(4))) unsigned int uint4v;
union U4S8 { uint4v u; short8 s; };

static __device__ __forceinline__ float lrelu(float x){ return x > 0.f ? x : 0.2f*x; }

// bf16 helpers (round-to-nearest-even)
static __device__ __forceinline__ unsigned short f2bf(float f){
  unsigned int u = __float_as_uint(f);
  unsigned int r = (u + 0x7fffu + ((u >> 16) & 1u)) >> 16;
  return (unsigned short)r;
}
static __device__ __forceinline__ float bf2f(unsigned short h){
  return __uint_as_float(((unsigned int)h) << 16);
}

// ---------------- CSR build ----------------
__global__ void k_deg(const int* __restrict__ ei, int* __restrict__ deg){
  int e = blockIdx.x*256 + threadIdx.x;
  if (e >= E_TOTC) return;
  int dst = (e < N_EDGESC) ? ei[N_EDGESC + e] : (e - N_EDGESC);
  atomicAdd(&deg[dst], 1);
}

__global__ __launch_bounds__(1024) void k_scan1(const int* __restrict__ deg,
                                                int* __restrict__ rowptr,
                                                int* __restrict__ bsum){
  __shared__ int s[1024];
  int t = threadIdx.x, i = blockIdx.x*1024 + t;
  int v = (i < N_NODESC) ? deg[i] : 0;
  s[t] = v; __syncthreads();
  for (int d = 1; d < 1024; d <<= 1){
    int xv = (t >= d) ? s[t-d] : 0;
    __syncthreads();
    s[t] += xv;
    __syncthreads();
  }
  if (i < N_NODESC) rowptr[i+1] = s[t];
  if (t == 1023) bsum[blockIdx.x] = s[t];
}

__global__ void k_scan2(int* __restrict__ bsum, int* __restrict__ rowptr, int nb){
  if (threadIdx.x == 0 && blockIdx.x == 0){
    int run = 0;
    for (int b = 0; b < nb; b++){ int v = bsum[b]; bsum[b] = run; run += v; }
    rowptr[0] = 0;
  }
}

__global__ __launch_bounds__(1024) void k_scan3(int* __restrict__ rowptr,
                                                const int* __restrict__ bsum){
  int i = blockIdx.x*1024 + threadIdx.x;
  if (i < N_NODESC) rowptr[i+1] += bsum[blockIdx.x];
}

__global__ void k_scatter(const int* __restrict__ ei, const int* __restrict__ rowptr,
                          int* __restrict__ cnt, int* __restrict__ esrc){
  int e = blockIdx.x*256 + threadIdx.x;
  if (e >= E_TOTC) return;
  int src, dst;
  if (e < N_EDGESC){ src = ei[e]; dst = ei[N_EDGESC + e]; }
  else { src = dst = e - N_EDGESC; }
  int pos = rowptr[dst] + atomicAdd(&cnt[dst], 1);
  esrc[pos] = src;
}

// ---------------- layer-1 attention logit precompute ----------------
__global__ void k_wa1(const float* __restrict__ W1, const float* __restrict__ a_src1,
                      const float* __restrict__ a_dst1, float* __restrict__ Wa1){
  int i = blockIdx.x*256 + threadIdx.x;
  if (i >= F_INC*2*HEADS1C) return;
  int d = i / (2*HEADS1C), c = i % (2*HEADS1C);
  const float* a = (c < HEADS1C) ? a_src1 : a_dst1;
  int h = (c < HEADS1C) ? c : c - HEADS1C;
  float s = 0.f;
  for (int j = 0; j < D1C; j++) s += W1[d*F1C + h*D1C + j] * a[h*D1C + j];
  Wa1[d*(2*HEADS1C) + c] = s;
}

// att1[n*20 + h] = alpha_src[n,h];  att1[n*20 + 10 + h] = alpha_dst[n,h]
__global__ void k_att1(const float* __restrict__ x, const float* __restrict__ Wa1,
                       float* __restrict__ att1){
  int i = blockIdx.x*256 + threadIdx.x;
  if (i >= N_NODESC*2*HEADS1C) return;
  int n = i / (2*HEADS1C), c = i % (2*HEADS1C);
  const float* xr = x + (size_t)n*F_INC;
  float s = 0.f;
  for (int d = 0; d < F_INC; d++) s += xr[d] * Wa1[d*(2*HEADS1C) + c];
  att1[i] = s;
}

__global__ void k_cast_bf(const float* __restrict__ in, ushort_t* __restrict__ o, int n){
  int i = blockIdx.x*256 + threadIdx.x;
  if (i < n) o[i] = f2bf(in[i]);
}

// one wave per node, ONLINE softmax, bf16 x gathers + next-edge prefetch
__global__ __launch_bounds__(64) void k_agg1(
    const ushort_t* __restrict__ xb, const float* __restrict__ att1,
    const int* __restrict__ rowptr, const int* __restrict__ esrc,
    ushort_t* __restrict__ zc, int base){
  __shared__ float xs[F_INC];
  __shared__ float al[HEADS1C];
  __shared__ float cr[HEADS1C];
  int n = base + blockIdx.x;
  int l = threadIdx.x;
  int b = rowptr[n], e = rowptr[n+1];
  float acc[15];
  #pragma unroll
  for (int k = 0; k < 15; k++) acc[k] = 0.f;
  int hk[15], dk[15];
  #pragma unroll
  for (int k = 0; k < 15; k++){ int f = l + 64*k; hk[k] = f/96; dk[k] = f%96; }
  float ad = 0.f, m = -1e30f, den = 0.f;
  if (l < HEADS1C) ad = att1[n*20 + 10 + l];
  int s_next = esrc[b];
  unsigned xu_next = (l < 39) ? *(const unsigned*)(xb + (size_t)s_next*F_INC + 2*l) : 0u;
  float at_next = (l < HEADS1C) ? att1[s_next*20 + l] : 0.f;
  for (int p = b; p < e; p++){
    unsigned xu = xu_next;
    float at = at_next;
    if (p + 1 < e){
      int s2 = esrc[p+1];
      if (l < 39) xu_next = *(const unsigned*)(xb + (size_t)s2*F_INC + 2*l);
      if (l < HEADS1C) at_next = att1[s2*20 + l];
    }
    if (l < 39){
      xs[2*l]   = bf2f((ushort_t)(xu & 0xffffu));
      xs[2*l+1] = bf2f((ushort_t)(xu >> 16));
    }
    if (l < HEADS1C){
      float ev = lrelu(at + ad);
      float mn = fmaxf(m, ev);
      float c  = expf(m - mn);
      float a  = expf(ev - mn);
      den = den*c + a;
      m = mn;
      al[l] = a; cr[l] = c;
    }
    __syncthreads();
    #pragma unroll
    for (int k = 0; k < 15; k++)
      if (dk[k] < 78) acc[k] = acc[k]*cr[hk[k]] + al[hk[k]]*xs[dk[k]];
    __syncthreads();
  }
  if (l < HEADS1C) al[l] = 1.f/(den + 1e-16f);
  __syncthreads();
  #pragma unroll
  for (int k = 0; k < 15; k++){
    int f = l + 64*k;
    float v = (dk[k] < 78) ? acc[k]*al[hk[k]] : 0.f;
    zc[(size_t)blockIdx.x*ZP + f] = f2bf(v);
  }
}

// ---------------- weight prep (zero-padded bf16) ----------------
__global__ void k_prepW1(const float* __restrict__ W1, ushort_t* __restrict__ W1t){
  // W1t[h][n(80)][k(96)] = bf16(W1[k][h*78+n]) with zero pad
  int i = blockIdx.x*256 + threadIdx.x;
  if (i >= HEADS1C*80*96) return;
  int h = i / (80*96), rem = i % (80*96), n = rem / 96, k = rem % 96;
  float v = (n < D1C && k < F_INC) ? W1[(size_t)k*F1C + h*D1C + n] : 0.f;
  W1t[i] = f2bf(v);
}

// W2p[n(128)][h*96+d] = bf16(W2[h*78+d][n]), zeros for d>=78
__global__ void k_prepW2p(const float* __restrict__ W2, ushort_t* __restrict__ W2p){
  int i = blockIdx.x*256 + threadIdx.x;
  if (i >= OUT2C*ZP) return;
  int n = i / ZP, kk = i % ZP;
  int h = kk / 96, d = kk % 96;
  float v = (d < D1C) ? W2[(size_t)(h*D1C + d)*OUT2C + n] : 0.f;
  W2p[i] = f2bf(v);
}

// generic: Wt[n][k(KB)] = bf16(W[k][n]) zero-padded in k
__global__ void k_prepWt(const float* __restrict__ W, ushort_t* __restrict__ Wt,
                         int Kdim, int Ndim, int KB){
  int i = blockIdx.x*256 + threadIdx.x;
  if (i >= Ndim*KB) return;
  int n = i / KB, k = i % KB;
  float v = (k < Kdim) ? W[(size_t)k*Ndim + n] : 0.f;
  Wt[i] = f2bf(v);
}

// ---------------- fused layer-1: h2pre = (elu(z @ bdW1 + b1)) @ W2 ----------
// v2: B fragments from global (L2 broadcast); LDS = A-tile + H-tile only
// (26.6 KB); 2 barriers per head; __launch_bounds__(256,3) for 3 blocks/CU.
__global__ __launch_bounds__(256, 3) void k_l1fused(
    const ushort_t* __restrict__ zc,   // [R][960]
    const ushort_t* __restrict__ W1t,  // [10][80][96]
    const float*    __restrict__ b1,   // [780]
    const ushort_t* __restrict__ W2p,  // [128][960]
    ushort_t* __restrict__ h2pre,      // [N][128]
    int R, int base)
{
  __shared__ unsigned int As[64][52];    // 64 x 96 bf16 (48 dwords) + pad
  __shared__ unsigned int Hs[64][52];    // h1 tile, same shape
  int m0 = blockIdx.x*64;
  int t = threadIdx.x;
  int w = t >> 6, lane = t & 63, q = lane >> 4, li = lane & 15;
  ushort_t* h1p = (ushort_t*)&Hs[0][0];  // row stride 104 ushorts
  f32x4 acc2[8];
  #pragma unroll
  for (int i = 0; i < 8; i++) acc2[i] = (f32x4){0.f,0.f,0.f,0.f};

  int ar = t >> 2;           // staged row 0..63 (4 threads per row)
  int ac = (t & 3) * 4;      // dword col base 0,4,8,12
  bool rv = (m0 + ar < R);

  for (int h = 0; h < HEADS1C; h++){
    // ---- stage A: 64 x 96 bf16, 3 x 16B per thread ----
    const uint4v* zrow = (const uint4v*)(zc + (size_t)(m0 + ar)*ZP + h*96);
    #pragma unroll
    for (int i = 0; i < 3; i++){
      uint4v v = rv ? zrow[(t & 3) + i*4] : (uint4v){0u,0u,0u,0u};
      *(uint4v*)&As[ar][ac + i*16] = v;
    }
    __syncthreads();                       // barrier 1: A ready (also fences prev GEMM2)
    // ---- GEMM1: 64x80 = A @ W1t[h]^T, B frags from global ----
    f32x4 acc1[5];
    #pragma unroll
    for (int i = 0; i < 5; i++) acc1[i] = (f32x4){0.f,0.f,0.f,0.f};
    #pragma unroll
    for (int kt = 0; kt < 3; kt++){
      U4S8 a; a.u = *(const uint4v*)&As[w*16 + li][kt*16 + q*4];
      const ushort_t* bp = W1t + (size_t)h*7680 + li*96 + kt*32 + q*8;
      #pragma unroll
      for (int nt = 0; nt < 5; nt++){
        U4S8 b; b.u = *(const uint4v*)(bp + nt*1536);   // +16 rows
        acc1[nt] = __builtin_amdgcn_mfma_f32_16x16x32_bf16(a.s, b.s, acc1[nt], 0,0,0);
      }
    }
    // ---- epilogue1: elu(h1 + b1) -> Hs (each wave writes its own 16 rows) ----
    #pragma unroll
    for (int nt = 0; nt < 5; nt++){
      int col = nt*16 + li;
      float bv = (col < D1C) ? b1[h*D1C + col] : 0.f;
      #pragma unroll
      for (int r = 0; r < 4; r++){
        int row = w*16 + q*4 + r;
        float v = acc1[nt][r] + bv;
        v = (v > 0.f) ? v : expm1f(v);
        if (col >= D1C) v = 0.f;
        h1p[row*104 + col] = f2bf(v);
      }
    }
    // zero pad cols 80..95 (dwords 40..47) of this wave's 16 rows
    #pragma unroll
    for (int i = 0; i < 2; i++){
      int idx = i*64 + lane;
      Hs[w*16 + (idx >> 3)][40 + (idx & 7)] = 0u;
    }
    __syncthreads();                       // barrier 2: H ready
    // ---- GEMM2: accumulate 64x128 += H @ W2p[:, h-slice]^T ----
    #pragma unroll
    for (int kt = 0; kt < 3; kt++){
      U4S8 a; a.u = *(const uint4v*)&Hs[w*16 + li][kt*16 + q*4];
      const ushort_t* bp = W2p + (size_t)li*ZP + h*96 + kt*32 + q*8;
      #pragma unroll
      for (int nt = 0; nt < 8; nt++){
        U4S8 b; b.u = *(const uint4v*)(bp + (size_t)nt*16*ZP);
        acc2[nt] = __builtin_amdgcn_mfma_f32_16x16x32_bf16(a.s, b.s, acc2[nt], 0,0,0);
      }
    }
    // no barrier here: next iteration's barrier 1 fences GEMM2 for all waves
  }
  // write h2pre tile
  #pragma unroll
  for (int nt = 0; nt < 8; nt++){
    int col = nt*16 + li;
    #pragma unroll
    for (int r = 0; r < 4; r++){
      int row = m0 + w*16 + q*4 + r;
      if (row < R)
        h2pre[(size_t)(base + row)*OUT2C + col] = f2bf(acc2[nt][r]);
    }
  }
}

// ---------------- MFMA bf16 GEMM (MLP head) ---------------------------------
template<int BN, int NT, int KB, int ACT, bool HASBIAS>
__global__ __launch_bounds__(256) void mfma_gemm(
    const ushort_t* __restrict__ A, const ushort_t* __restrict__ Bt,
    const float* __restrict__ bias, ushort_t* __restrict__ C,
    int M, int N, int K, int lda, int ldc)
{
  __shared__ unsigned int As[64][20];   // 64 rows x 32 bf16 (+pad)
  __shared__ unsigned int Bs[BN][20];
  int m0 = blockIdx.x*64;
  int n0 = blockIdx.y*BN;
  int t = threadIdx.x;
  int w = t >> 6, lane = t & 63;
  int q = lane >> 4, li = lane & 15;
  f32x4 acc[NT];
  #pragma unroll
  for (int i = 0; i < NT; i++) acc[i] = (f32x4){0.f,0.f,0.f,0.f};

  int am = t >> 2;
  int ak0 = (t & 3)*8;
  int gm = m0 + am;

  for (int kt = 0; kt < KB; kt += 32){
    {
      unsigned int u0,u1,u2,u3;
      int gk = kt + ak0;
      if (gm < M && gk + 8 <= K){
        const unsigned int* ap = (const unsigned int*)(A + (size_t)gm*lda + gk);
        u0 = ap[0]; u1 = ap[1]; u2 = ap[2]; u3 = ap[3];
      } else {
        ushort_t tmp[8];
        #pragma unroll
        for (int j = 0; j < 8; j++)
          tmp[j] = (gm < M && gk + j < K) ? A[(size_t)gm*lda + gk + j] : (ushort_t)0;
        u0 = tmp[0] | ((unsigned)tmp[1]<<16);
        u1 = tmp[2] | ((unsigned)tmp[3]<<16);
        u2 = tmp[4] | ((unsigned)tmp[5]<<16);
        u3 = tmp[6] | ((unsigned)tmp[7]<<16);
      }
      int c0 = (t & 3)*4;
      As[am][c0] = u0; As[am][c0+1] = u1; As[am][c0+2] = u2; As[am][c0+3] = u3;
    }
    for (int g = t; g < BN*4; g += 256){
      int n = g >> 2, c0 = (g & 3)*4;
      const unsigned int* bp = (const unsigned int*)(Bt + (size_t)(n0 + n)*KB + kt + c0*2);
      Bs[n][c0] = bp[0]; Bs[n][c0+1] = bp[1]; Bs[n][c0+2] = bp[2]; Bs[n][c0+3] = bp[3];
    }
    __syncthreads();
    U4S8 a; a.u = *(const uint4v*)&As[w*16 + li][q*4];
    #pragma unroll
    for (int nt = 0; nt < NT; nt++){
      U4S8 b; b.u = *(const uint4v*)&Bs[nt*16 + li][q*4];
      acc[nt] = __builtin_amdgcn_mfma_f32_16x16x32_bf16(a.s, b.s, acc[nt], 0, 0, 0);
    }
    __syncthreads();
  }
  #pragma unroll
  for (int nt = 0; nt < NT; nt++){
    int col = n0 + nt*16 + li;
    if (col >= N) continue;
    float bv = HASBIAS ? bias[col] : 0.f;
    #pragma unroll
    for (int r = 0; r < 4; r++){
      int gmr = m0 + w*16 + q*4 + r;
      if (gmr >= M) continue;
      float v = acc[nt][r] + bv;
      if (ACT == 1) v = fmaxf(v, 0.f);
      else if (ACT == 2) v = (v > 0.f) ? v : expm1f(v);
      C[(size_t)gmr*ldc + col] = f2bf(v);
    }
  }
}

// ---------------- layer-2 attention ----------------
__global__ void k_att2(const ushort_t* __restrict__ h2pre,
                       const float* __restrict__ a_src2,
                       const float* __restrict__ a_dst2, float* __restrict__ att2){
  int n = blockIdx.x*4 + (threadIdx.x >> 6);
  int l = threadIdx.x & 63;
  if (n >= N_NODESC) return;
  const ushort_t* r = h2pre + (size_t)n*OUT2C;
  float v0 = bf2f(r[l]), v1 = bf2f(r[64+l]);
  float p0 = v0*a_src2[l] + v1*a_src2[64+l];
  float p1 = v0*a_dst2[l] + v1*a_dst2[64+l];
  #pragma unroll
  for (int off = 32; off; off >>= 1){
    p0 += __shfl_xor(p0, off);
    p1 += __shfl_xor(p1, off);
  }
  if (l == 0){ att2[n*2] = p0; att2[n*2+1] = p1; }
}

// layer-2 aggregation with ONLINE softmax (stats2 fused away), uint gathers,
// next-edge prefetch; bf16 h2 out + sigmoid gate
__global__ void k_agg2(const ushort_t* __restrict__ h2pre,
                       const float* __restrict__ att2,
                       const int* __restrict__ rowptr, const int* __restrict__ esrc,
                       const float* __restrict__ b2,
                       const float* __restrict__ w_gate, const float* __restrict__ b_gate,
                       ushort_t* __restrict__ h2b, float* __restrict__ wnode){
  int n = blockIdx.x*4 + (threadIdx.x >> 6);
  int l = threadIdx.x & 63;
  if (n >= N_NODESC) return;
  float ad = att2[n*2+1];
  int b = rowptr[n], e = rowptr[n+1];
  float m = -1e30f, den = 0.f, a0 = 0.f, a1 = 0.f;
  int s_next = esrc[b];
  unsigned u_next = *(const unsigned*)(h2pre + (size_t)s_next*OUT2C + 2*l);
  float at_next = att2[s_next*2];
  for (int p = b; p < e; p++){
    unsigned u = u_next;
    float at = at_next;
    if (p + 1 < e){
      int s2 = esrc[p+1];
      u_next = *(const unsigned*)(h2pre + (size_t)s2*OUT2C + 2*l);
      at_next = att2[s2*2];
    }
    float ev = lrelu(at + ad);
    float mn = fmaxf(m, ev);
    float c = expf(m - mn), a = expf(ev - mn);
    den = den*c + a; m = mn;
    a0 = a0*c + a*bf2f((ushort_t)(u & 0xffffu));
    a1 = a1*c + a*bf2f((ushort_t)(u >> 16));
  }
  float rd = 1.f/(den + 1e-16f);
  float v0 = fmaxf(a0*rd + b2[2*l],   0.f);
  float v1 = fmaxf(a1*rd + b2[2*l+1], 0.f);
  unsigned hv = (unsigned)f2bf(v0) | ((unsigned)f2bf(v1) << 16);
  *(unsigned*)(h2b + (size_t)n*OUT2C + 2*l) = hv;
  float pp = v0*w_gate[2*l] + v1*w_gate[2*l+1];
  #pragma unroll
  for (int off = 32; off; off >>= 1) pp += __shfl_xor(pp, off);
  if (l == 0) wnode[n] = 1.f/(1.f + expf(-(pp + b_gate[0])));
}

// one block per graph: weighted-sum + max readout, bf16 in/out
__global__ __launch_bounds__(128) void k_readout(const ushort_t* __restrict__ h2b,
                                                 const float* __restrict__ wnode,
                                                 const int* __restrict__ batch,
                                                 ushort_t* __restrict__ xcb){
  __shared__ int lohi[2];
  int g = blockIdx.x, t = threadIdx.x;
  if (t == 0){
    int lo = 0, hi = N_NODESC;
    while (lo < hi){ int mid = (lo+hi) >> 1; if (batch[mid] < g) lo = mid+1; else hi = mid; }
    lohi[0] = lo;
    int lo2 = lo; hi = N_NODESC;
    while (lo2 < hi){ int mid = (lo2+hi) >> 1; if (batch[mid] < g+1) lo2 = mid+1; else hi = mid; }
    lohi[1] = lo2;
  }
  __syncthreads();
  int lo = lohi[0], hi = lohi[1];
  float sum = 0.f, mx = 0.f;
  for (int n = lo; n < hi; n++){
    float v = bf2f(h2b[(size_t)n*OUT2C + t]);
    sum += v * wnode[n];
    mx = fmaxf(mx, v);
  }
  xcb[(size_t)g*512 + t] = f2bf(sum);
  xcb[(size_t)g*512 + 128 + t] = f2bf(mx);
}

__global__ void k_final(const ushort_t* __restrict__ f2b, const float* __restrict__ W_out,
                        const float* __restrict__ b_out, float* __restrict__ out){
  int g = blockIdx.x*4 + (threadIdx.x >> 6);
  int l = threadIdx.x & 63;
  if (g >= N_GRAPHSC) return;
  float s = 0.f;
  #pragma unroll
  for (int k = 0; k < 4; k++) s += bf2f(f2b[(size_t)g*256 + l + 64*k]) * W_out[l + 64*k];
  #pragma unroll
  for (int off = 32; off; off >>= 1) s += __shfl_xor(s, off);
  if (l == 0) out[g] = s + b_out[0];
}

extern "C" void kernel_launch(void* const* d_in, const int* in_sizes, int n_in,
                              void* d_out, int out_size, void* d_ws, size_t ws_size,
                              hipStream_t stream) {
  const float* x      = (const float*)d_in[0];
  const int*   ei     = (const int*)d_in[1];
  const int*   batch  = (const int*)d_in[2];
  const float* target = (const float*)d_in[3];
  const float* W1     = (const float*)d_in[4];
  const float* a_src1 = (const float*)d_in[5];
  const float* a_dst1 = (const float*)d_in[6];
  const float* b1     = (const float*)d_in[7];
  const float* W2     = (const float*)d_in[8];
  const float* a_src2 = (const float*)d_in[9];
  const float* a_dst2 = (const float*)d_in[10];
  const float* b2     = (const float*)d_in[11];
  const float* w_gate = (const float*)d_in[12];
  const float* b_gate = (const float*)d_in[13];
  const float* W_xt   = (const float*)d_in[14];
  const float* b_xt   = (const float*)d_in[15];
  const float* W_fc1  = (const float*)d_in[16];
  const float* b_fc1  = (const float*)d_in[17];
  const float* W_fc2  = (const float*)d_in[18];
  const float* b_fc2  = (const float*)d_in[19];
  const float* W_out  = (const float*)d_in[20];
  const float* b_out  = (const float*)d_in[21];
  float* out = (float*)d_out;

  // ---- adaptive chunking so the carve fits ws_size ----
  const size_t MB = (size_t)1 << 20;
  int C;
  if      (ws_size >= 285*MB) C = 1;   // ~262 MB
  else if (ws_size >= 190*MB) C = 2;   // ~166 MB
  else                        C = 4;   // ~118 MB
  const int R = N_NODESC / C;

  char* p = (char*)d_ws;
  auto carve = [&](size_t bytes) -> char* {
    char* r = p; p += (bytes + 255) & ~(size_t)255; return r;
  };
  int*   deg    = (int*)  carve((size_t)N_NODESC*4);
  int*   rowptr = (int*)  carve((size_t)(N_NODESC+1)*4);
  int*   cnt    = (int*)  carve((size_t)N_NODESC*4);
  int*   esrc   = (int*)  carve((size_t)E_TOTC*4);
  int*   bsum   = (int*)  carve(128*4);
  float* Wa1    = (float*)carve((size_t)F_INC*20*4);
  float* att1   = (float*)carve((size_t)N_NODESC*20*4);
  float* att2   = (float*)carve((size_t)N_NODESC*2*4);
  float* wnode  = (float*)carve((size_t)N_NODESC*4);
  ushort_t* W1t   = (ushort_t*)carve((size_t)HEADS1C*80*96*2);
  ushort_t* W2p   = (ushort_t*)carve((size_t)OUT2C*ZP*2);
  ushort_t* Wxtt  = (ushort_t*)carve((size_t)256*1280*2);
  ushort_t* Wfc1t = (ushort_t*)carve((size_t)1024*512*2);
  ushort_t* Wfc2t = (ushort_t*)carve((size_t)256*1024*2);
  ushort_t* tb    = (ushort_t*)carve((size_t)N_GRAPHSC*1280*2);
  ushort_t* xb    = (ushort_t*)carve((size_t)N_NODESC*F_INC*2);
  ushort_t* h2pre = (ushort_t*)carve((size_t)N_NODESC*OUT2C*2);
  ushort_t* xcb   = (ushort_t*)carve((size_t)N_GRAPHSC*512*2);
  ushort_t* f1b   = (ushort_t*)carve((size_t)N_GRAPHSC*1024*2);
  ushort_t* f2b   = (ushort_t*)carve((size_t)N_GRAPHSC*256*2);
  size_t big_bytes = (size_t)R*ZP*2;                    // zc (bf16, padded)
  size_t h2_bytes  = (size_t)N_NODESC*OUT2C*2;          // h2b (bf16)
  char*  BIG = carve(big_bytes > h2_bytes ? big_bytes : h2_bytes);
  ushort_t* zc  = (ushort_t*)BIG;
  ushort_t* h2b = (ushort_t*)BIG;   // overlays zc AFTER all k_l1fused chunks

  hipMemsetAsync(deg, 0, (size_t)N_NODESC*4, stream);
  hipMemsetAsync(cnt, 0, (size_t)N_NODESC*4, stream);

  // CSR by destination (self-loops appended)
  k_deg<<<(E_TOTC+255)/256, 256, 0, stream>>>(ei, deg);
  int nb = (N_NODESC + 1023)/1024;
  k_scan1<<<nb, 1024, 0, stream>>>(deg, rowptr, bsum);
  k_scan2<<<1, 64, 0, stream>>>(bsum, rowptr, nb);
  k_scan3<<<nb, 1024, 0, stream>>>(rowptr, bsum);
  k_scatter<<<(E_TOTC+255)/256, 256, 0, stream>>>(ei, rowptr, cnt, esrc);

  // weight prep (bf16, zero-padded) + casts
  k_prepW1<<<(HEADS1C*80*96+255)/256, 256, 0, stream>>>(W1, W1t);
  k_prepW2p<<<(OUT2C*ZP+255)/256, 256, 0, stream>>>(W2, W2p);
  k_prepWt<<<(256*1280+255)/256, 256, 0, stream>>>(W_xt, Wxtt, 1280, 256, 1280);
  k_prepWt<<<(1024*512+255)/256, 256, 0, stream>>>(W_fc1, Wfc1t, 512, 1024, 512);
  k_prepWt<<<(256*1024+255)/256, 256, 0, stream>>>(W_fc2, Wfc2t, 1024, 256, 1024);
  k_cast_bf<<<((N_GRAPHSC*1280)+255)/256, 256, 0, stream>>>(target, tb, N_GRAPHSC*1280);
  k_cast_bf<<<((N_NODESC*F_INC)+255)/256, 256, 0, stream>>>(x, xb, N_NODESC*F_INC);

  // layer-1 attention logits via folded weights
  k_wa1<<<(F_INC*20+255)/256, 256, 0, stream>>>(W1, a_src1, a_dst1, Wa1);
  k_att1<<<(N_NODESC*20+255)/256, 256, 0, stream>>>(x, Wa1, att1);

  // layer-1 (chunked): online-softmax agg -> zc; fused double-GEMM -> h2pre
  for (int c = 0; c < C; c++){
    int base = c*R;
    k_agg1<<<R, 64, 0, stream>>>(xb, att1, rowptr, esrc, zc, base);
    k_l1fused<<<(R+63)/64, 256, 0, stream>>>(zc, W1t, b1, W2p, h2pre, R, base);
  }

  // layer-2 attention + fused online-softmax aggregation (h2b overlays zc)
  k_att2<<<(N_NODESC+3)/4, 256, 0, stream>>>(h2pre, a_src2, a_dst2, att2);
  k_agg2<<<(N_NODESC+3)/4, 256, 0, stream>>>(h2pre, att2, rowptr, esrc,
                                             b2, w_gate, b_gate, h2b, wnode);

  // readout (bf16) + MLP head via MFMA
  k_readout<<<N_GRAPHSC, 128, 0, stream>>>(h2b, wnode, batch, xcb);
  mfma_gemm<128,8,1280,0,true><<<dim3(N_GRAPHSC/64, 256/128, 1), 256, 0, stream>>>(
      tb, Wxtt, b_xt, xcb + 256, N_GRAPHSC, 256, 1280, 1280, 512);
  mfma_gemm<128,8,512,1,true><<<dim3(N_GRAPHSC/64, 1024/128, 1), 256, 0, stream>>>(
      xcb, Wfc1t, b_fc1, f1b, N_GRAPHSC, 1024, 512, 512, 1024);
  mfma_gemm<128,8,1024,1,true><<<dim3(N_GRAPHSC/64, 256/128, 1), 256, 0, stream>>>(
      f1b, Wfc2t, b_fc2, f2b, N_GRAPHSC, 256, 1024, 1024, 256);
  k_final<<<(N_GRAPHSC+3)/4, 256, 0, stream>>>(f2b, W_out, b_out, out);
}

// Round 7
// 792.870 us; speedup vs baseline: 1.3685x; 1.3204x over previous
//
#include <hip/hip_runtime.h>
#include <cstdint>
#include <cstddef>

#define N_NODESC 100000
#define N_EDGESC 400000
#define N_GRAPHSC 2048
#define F_INC 78
#define HEADS1C 10
#define D1C 78           // per-head out dim, layer 1
#define F1C 780          // HEADS1C * D1C
#define OUT2C 128
#define E_TOTC (N_EDGESC + N_NODESC)   // 500000 edges incl. self-loops

typedef unsigned short ushort_t;
typedef __attribute__((ext_vector_type(8))) short short8;
typedef __attribute__((ext_vector_type(4))) float f32x4;
typedef __attribute__((ext_vector_type(4))) unsigned int uint4v;
union U4S8 { uint4v u; short8 s; };

static __device__ __forceinline__ float lrelu(float x){ return x > 0.f ? x : 0.2f*x; }

// bf16 helpers (round-to-nearest-even)
static __device__ __forceinline__ unsigned short f2bf(float f){
  unsigned int u = __float_as_uint(f);
  unsigned int r = (u + 0x7fffu + ((u >> 16) & 1u)) >> 16;
  return (unsigned short)r;
}
static __device__ __forceinline__ float bf2f(unsigned short h){
  return __uint_as_float(((unsigned int)h) << 16);
}

// ---------------- CSR build ----------------
__global__ void k_deg(const int* __restrict__ ei, int* __restrict__ deg){
  int e = blockIdx.x*256 + threadIdx.x;
  if (e >= E_TOTC) return;
  int dst = (e < N_EDGESC) ? ei[N_EDGESC + e] : (e - N_EDGESC);
  atomicAdd(&deg[dst], 1);
}

__global__ __launch_bounds__(1024) void k_scan1(const int* __restrict__ deg,
                                                int* __restrict__ rowptr,
                                                int* __restrict__ bsum){
  __shared__ int s[1024];
  int t = threadIdx.x, i = blockIdx.x*1024 + t;
  int v = (i < N_NODESC) ? deg[i] : 0;
  s[t] = v; __syncthreads();
  for (int d = 1; d < 1024; d <<= 1){
    int xv = (t >= d) ? s[t-d] : 0;
    __syncthreads();
    s[t] += xv;
    __syncthreads();
  }
  if (i < N_NODESC) rowptr[i+1] = s[t];
  if (t == 1023) bsum[blockIdx.x] = s[t];
}

__global__ void k_scan2(int* __restrict__ bsum, int* __restrict__ rowptr, int nb){
  if (threadIdx.x == 0 && blockIdx.x == 0){
    int run = 0;
    for (int b = 0; b < nb; b++){ int v = bsum[b]; bsum[b] = run; run += v; }
    rowptr[0] = 0;
  }
}

__global__ __launch_bounds__(1024) void k_scan3(int* __restrict__ rowptr,
                                                const int* __restrict__ bsum){
  int i = blockIdx.x*1024 + threadIdx.x;
  if (i < N_NODESC) rowptr[i+1] += bsum[blockIdx.x];
}

__global__ void k_scatter(const int* __restrict__ ei, const int* __restrict__ rowptr,
                          int* __restrict__ cnt, int* __restrict__ esrc){
  int e = blockIdx.x*256 + threadIdx.x;
  if (e >= E_TOTC) return;
  int src, dst;
  if (e < N_EDGESC){ src = ei[e]; dst = ei[N_EDGESC + e]; }
  else { src = dst = e - N_EDGESC; }
  int pos = rowptr[dst] + atomicAdd(&cnt[dst], 1);
  esrc[pos] = src;
}

// ---------------- layer-1 attention logit precompute ----------------
__global__ void k_wa1(const float* __restrict__ W1, const float* __restrict__ a_src1,
                      const float* __restrict__ a_dst1, float* __restrict__ Wa1){
  int i = blockIdx.x*256 + threadIdx.x;
  if (i >= F_INC*2*HEADS1C) return;
  int d = i / (2*HEADS1C), c = i % (2*HEADS1C);
  const float* a = (c < HEADS1C) ? a_src1 : a_dst1;
  int h = (c < HEADS1C) ? c : c - HEADS1C;
  float s = 0.f;
  for (int j = 0; j < D1C; j++) s += W1[d*F1C + h*D1C + j] * a[h*D1C + j];
  Wa1[d*(2*HEADS1C) + c] = s;
}

// att1[n*20 + h] = alpha_src[n,h];  att1[n*20 + 10 + h] = alpha_dst[n,h]
__global__ void k_att1(const float* __restrict__ x, const float* __restrict__ Wa1,
                       float* __restrict__ att1){
  int i = blockIdx.x*256 + threadIdx.x;
  if (i >= N_NODESC*2*HEADS1C) return;
  int n = i / (2*HEADS1C), c = i % (2*HEADS1C);
  const float* xr = x + (size_t)n*F_INC;
  float s = 0.f;
  for (int d = 0; d < F_INC; d++) s += xr[d] * Wa1[d*(2*HEADS1C) + c];
  att1[i] = s;
}

// per (node, head): max + 1/(sum exp + 1e-16), 4-edge-deep loads
__global__ void k_stats1(const float* __restrict__ att1, const int* __restrict__ rowptr,
                         const int* __restrict__ esrc, float* __restrict__ stat1){
  int i = blockIdx.x*256 + threadIdx.x;
  if (i >= N_NODESC*HEADS1C) return;
  int n = i / HEADS1C, h = i % HEADS1C;
  float ad = att1[n*20 + 10 + h];
  int b = rowptr[n], e = rowptr[n+1];
  float m = -1e30f;
  for (int p = b; p < e; p += 4){
    int c = e - p; if (c > 4) c = 4;
    float v[4];
    #pragma unroll
    for (int j = 0; j < 4; j++){ int s = esrc[p + (j < c ? j : 0)]; v[j] = att1[s*20 + h]; }
    #pragma unroll
    for (int j = 0; j < 4; j++) if (j < c) m = fmaxf(m, lrelu(v[j] + ad));
  }
  float den = 0.f;
  for (int p = b; p < e; p += 4){
    int c = e - p; if (c > 4) c = 4;
    float v[4];
    #pragma unroll
    for (int j = 0; j < 4; j++){ int s = esrc[p + (j < c ? j : 0)]; v[j] = att1[s*20 + h]; }
    #pragma unroll
    for (int j = 0; j < 4; j++) if (j < c) den += expf(lrelu(v[j] + ad) - m);
  }
  stat1[n*20 + h] = m;
  stat1[n*20 + 10 + h] = 1.f/(den + 1e-16f);
}

// one wave per node, 4-edge-deep: zc[local, h*78+d] = sum_e alpha[e,h]*x[src,d]
__global__ __launch_bounds__(64) void k_agg1(
    const float* __restrict__ x, const float* __restrict__ att1,
    const float* __restrict__ stat1, const int* __restrict__ rowptr,
    const int* __restrict__ esrc, ushort_t* __restrict__ zc, int base){
  __shared__ float xs[4][F_INC];
  __shared__ float al[4][HEADS1C];
  int n = base + blockIdx.x;
  int l = threadIdx.x;
  int b = rowptr[n], e = rowptr[n+1];
  float acc[13];
  #pragma unroll
  for (int k = 0; k < 13; k++) acc[k] = 0.f;
  int hk[13], dk[13];
  #pragma unroll
  for (int k = 0; k < 13; k++){ int f = l + 64*k; hk[k] = f/78; dk[k] = f%78; }
  float ad = 0.f, mm = 0.f, rd = 0.f;
  if (l < HEADS1C){
    ad = att1[n*20 + 10 + l];
    mm = stat1[n*20 + l];
    rd = stat1[n*20 + 10 + l];
  }
  for (int p = b; p < e; p += 4){
    int c = e - p; if (c > 4) c = 4;
    int ss[4];
    #pragma unroll
    for (int j = 0; j < 4; j++) ss[j] = esrc[p + (j < c ? j : 0)];
    if (l < 39){
      #pragma unroll
      for (int j = 0; j < 4; j++){
        float2 v = *(const float2*)(x + (size_t)ss[j]*F_INC + 2*l);
        xs[j][2*l] = v.x; xs[j][2*l+1] = v.y;
      }
    }
    if (l < HEADS1C){
      #pragma unroll
      for (int j = 0; j < 4; j++){
        float ev = lrelu(att1[ss[j]*20 + l] + ad);
        al[j][l] = (j < c) ? expf(ev - mm) * rd : 0.f;
      }
    }
    __syncthreads();
    #pragma unroll
    for (int k = 0; k < 13; k++){
      int f = l + 64*k;
      if (f < F1C){
        float s = al[0][hk[k]]*xs[0][dk[k]] + al[1][hk[k]]*xs[1][dk[k]]
                + al[2][hk[k]]*xs[2][dk[k]] + al[3][hk[k]]*xs[3][dk[k]];
        acc[k] += s;
      }
    }
    __syncthreads();
  }
  #pragma unroll
  for (int k = 0; k < 13; k++){
    int f = l + 64*k;
    if (f < F1C) zc[(size_t)blockIdx.x*F1C + f] = f2bf(acc[k]);
  }
}

// ---------------- weight pre-transpose (zero-padded bf16) ----------------
__global__ void k_prepW1(const float* __restrict__ W1, ushort_t* __restrict__ W1t){
  // W1t[h][n(80)][k(96)] = bf16(W1[k][h*78+n]) with zero pad
  int i = blockIdx.x*256 + threadIdx.x;
  if (i >= HEADS1C*80*96) return;
  int h = i / (80*96), rem = i % (80*96), n = rem / 96, k = rem % 96;
  float v = (n < D1C && k < F_INC) ? W1[(size_t)k*F1C + h*D1C + n] : 0.f;
  W1t[i] = f2bf(v);
}

// generic: Wt[n][k(KB)] = bf16(W[k][n]) zero-padded in k
__global__ void k_prepWt(const float* __restrict__ W, ushort_t* __restrict__ Wt,
                         int Kdim, int Ndim, int KB){
  int i = blockIdx.x*256 + threadIdx.x;
  if (i >= Ndim*KB) return;
  int n = i / KB, k = i % KB;
  float v = (k < Kdim) ? W[(size_t)k*Ndim + n] : 0.f;
  Wt[i] = f2bf(v);
}

__global__ void k_cast_bf(const float* __restrict__ in, ushort_t* __restrict__ o, int n){
  int i = blockIdx.x*256 + threadIdx.x;
  if (i < n) o[i] = f2bf(in[i]);
}

// ---------------- MFMA bf16 GEMM: C[M,N] = act(A @ Bt^T + bias), bf16 out ---
// A: bf16 [M rows, lda stride]; Bt: bf16 [BN][KB] zero-padded (KB % 32 == 0).
// KVAL = valid columns of the LAST 32-wide k-tile (even, 2..32). All A staging
// is fast-path 16B loads with compile-time dword masks (no byte assembly).
// Block: 64 rows x BN cols; 4 waves. ACT: 0 none, 1 relu, 2 elu.
template<int BN, int NT, int KB, int KVAL, int ACT, bool HASBIAS>
__global__ __launch_bounds__(256) void mfma_gemm(
    const ushort_t* __restrict__ A, const ushort_t* __restrict__ Bt,
    const float* __restrict__ bias, ushort_t* __restrict__ C,
    int M, int N, int lda, int ldc,
    int zsA, int zsBt, int zsC, int zsBias)
{
  __shared__ unsigned int As[64][20];   // 64 rows x 32 bf16 (+pad)
  __shared__ unsigned int Bs[BN][20];
  int z = blockIdx.z;
  A += (size_t)z*zsA; Bt += (size_t)z*zsBt; C += (size_t)z*zsC;
  const float* bz = HASBIAS ? (bias + (size_t)z*zsBias) : nullptr;
  int m0 = blockIdx.x*64;
  int n0 = blockIdx.y*BN;
  int t = threadIdx.x;
  int w = t >> 6, lane = t & 63;
  int q = lane >> 4, li = lane & 15;
  f32x4 acc[NT];
  #pragma unroll
  for (int i = 0; i < NT; i++) acc[i] = (f32x4){0.f,0.f,0.f,0.f};

  int am = t >> 2;           // staged row 0..63
  int ak0 = (t & 3)*8;       // short col base 0,8,16,24
  int gm = m0 + am;
  bool rv = (gm < M);

  #pragma unroll
  for (int ki = 0; ki < KB/32; ki++){
    const int kt = ki*32;
    // valid shorts this iter for this thread (compile-time for non-last iters)
    int nv;
    if (ki == KB/32 - 1){
      int d = KVAL - ak0; nv = d < 0 ? 0 : (d > 8 ? 8 : d);
    } else nv = 8;
    {
      unsigned u0=0u, u1=0u, u2=0u, u3=0u;
      if (rv && nv > 0){
        const unsigned int* ap = (const unsigned int*)(A + (size_t)gm*lda + kt + ak0);
        u0 = ap[0]; u1 = ap[1]; u2 = ap[2]; u3 = ap[3];
        int ndw = nv >> 1;
        if (ndw < 4) u3 = 0u;
        if (ndw < 3) u2 = 0u;
        if (ndw < 2) u1 = 0u;
      }
      int c0 = (t & 3)*4;
      As[am][c0] = u0; As[am][c0+1] = u1; As[am][c0+2] = u2; As[am][c0+3] = u3;
    }
    for (int g = t; g < BN*4; g += 256){
      int n = g >> 2, c0 = (g & 3)*4;
      const unsigned int* bp = (const unsigned int*)(Bt + (size_t)(n0 + n)*KB + kt + c0*2);
      Bs[n][c0] = bp[0]; Bs[n][c0+1] = bp[1]; Bs[n][c0+2] = bp[2]; Bs[n][c0+3] = bp[3];
    }
    __syncthreads();
    U4S8 a; a.u = *(const uint4v*)&As[w*16 + li][q*4];
    #pragma unroll
    for (int nt = 0; nt < NT; nt++){
      U4S8 b; b.u = *(const uint4v*)&Bs[nt*16 + li][q*4];
      acc[nt] = __builtin_amdgcn_mfma_f32_16x16x32_bf16(a.s, b.s, acc[nt], 0, 0, 0);
    }
    __syncthreads();
  }
  #pragma unroll
  for (int nt = 0; nt < NT; nt++){
    int col = n0 + nt*16 + li;
    if (col >= N) continue;
    float bv = HASBIAS ? bz[col] : 0.f;
    #pragma unroll
    for (int r = 0; r < 4; r++){
      int gmr = m0 + w*16 + q*4 + r;
      if (gmr >= M) continue;
      float v = acc[nt][r] + bv;
      if (ACT == 1) v = fmaxf(v, 0.f);
      else if (ACT == 2) v = (v > 0.f) ? v : expm1f(v);
      C[(size_t)gmr*ldc + col] = f2bf(v);
    }
  }
}

// ---------------- layer-2 attention ----------------
__global__ void k_att2(const ushort_t* __restrict__ h2pre,
                       const float* __restrict__ a_src2,
                       const float* __restrict__ a_dst2, float* __restrict__ att2){
  int n = blockIdx.x*4 + (threadIdx.x >> 6);
  int l = threadIdx.x & 63;
  if (n >= N_NODESC) return;
  const ushort_t* r = h2pre + (size_t)n*OUT2C;
  float v0 = bf2f(r[l]), v1 = bf2f(r[64+l]);
  float p0 = v0*a_src2[l] + v1*a_src2[64+l];
  float p1 = v0*a_dst2[l] + v1*a_dst2[64+l];
  #pragma unroll
  for (int off = 32; off; off >>= 1){
    p0 += __shfl_xor(p0, off);
    p1 += __shfl_xor(p1, off);
  }
  if (l == 0){ att2[n*2] = p0; att2[n*2+1] = p1; }
}

// per node: max + 1/(sum exp), 4-edge-deep loads
__global__ void k_stats2(const float* __restrict__ att2, const int* __restrict__ rowptr,
                         const int* __restrict__ esrc, float* __restrict__ stat2){
  int n = blockIdx.x*256 + threadIdx.x;
  if (n >= N_NODESC) return;
  float ad = att2[n*2+1];
  int b = rowptr[n], e = rowptr[n+1];
  float m = -1e30f;
  for (int p = b; p < e; p += 4){
    int c = e - p; if (c > 4) c = 4;
    float v[4];
    #pragma unroll
    for (int j = 0; j < 4; j++){ int s = esrc[p + (j < c ? j : 0)]; v[j] = att2[s*2]; }
    #pragma unroll
    for (int j = 0; j < 4; j++) if (j < c) m = fmaxf(m, lrelu(v[j] + ad));
  }
  float den = 0.f;
  for (int p = b; p < e; p += 4){
    int c = e - p; if (c > 4) c = 4;
    float v[4];
    #pragma unroll
    for (int j = 0; j < 4; j++){ int s = esrc[p + (j < c ? j : 0)]; v[j] = att2[s*2]; }
    #pragma unroll
    for (int j = 0; j < 4; j++) if (j < c) den += expf(lrelu(v[j] + ad) - m);
  }
  stat2[n*2] = m;
  stat2[n*2+1] = 1.f/(den + 1e-16f);
}

// wave per node, 4-edge-deep coalesced pair gathers; fp32 h2 + sigmoid gate
__global__ void k_agg2(const ushort_t* __restrict__ h2pre,
                       const float* __restrict__ att2,
                       const float* __restrict__ stat2, const int* __restrict__ rowptr,
                       const int* __restrict__ esrc, const float* __restrict__ b2,
                       const float* __restrict__ w_gate, const float* __restrict__ b_gate,
                       float* __restrict__ h2, float* __restrict__ wnode){
  int n = blockIdx.x*4 + (threadIdx.x >> 6);
  int l = threadIdx.x & 63;
  if (n >= N_NODESC) return;
  float ad = att2[n*2+1], m = stat2[n*2], rd = stat2[n*2+1];
  int b = rowptr[n], e = rowptr[n+1];
  float a0 = 0.f, a1 = 0.f;
  for (int p = b; p < e; p += 4){
    int c = e - p; if (c > 4) c = 4;
    int ss[4];
    #pragma unroll
    for (int j = 0; j < 4; j++) ss[j] = esrc[p + (j < c ? j : 0)];
    unsigned u[4]; float at[4];
    #pragma unroll
    for (int j = 0; j < 4; j++) u[j] = *(const unsigned*)(h2pre + (size_t)ss[j]*OUT2C + 2*l);
    #pragma unroll
    for (int j = 0; j < 4; j++) at[j] = att2[ss[j]*2];
    #pragma unroll
    for (int j = 0; j < 4; j++){
      if (j < c){
        float alpha = expf(lrelu(at[j] + ad) - m) * rd;
        a0 += alpha * bf2f((ushort_t)(u[j] & 0xffffu));
        a1 += alpha * bf2f((ushort_t)(u[j] >> 16));
      }
    }
  }
  float v0 = fmaxf(a0 + b2[2*l],   0.f);
  float v1 = fmaxf(a1 + b2[2*l+1], 0.f);
  float2 hv; hv.x = v0; hv.y = v1;
  *(float2*)(h2 + (size_t)n*OUT2C + 2*l) = hv;
  float pp = v0*w_gate[2*l] + v1*w_gate[2*l+1];
  #pragma unroll
  for (int off = 32; off; off >>= 1) pp += __shfl_xor(pp, off);
  if (l == 0) wnode[n] = 1.f/(1.f + expf(-(pp + b_gate[0])));
}

// one block per graph: weighted-sum + max readout, bf16 out into xcb[:, 0:256]
__global__ __launch_bounds__(128) void k_readout(const float* __restrict__ h2,
                                                 const float* __restrict__ wnode,
                                                 const int* __restrict__ batch,
                                                 ushort_t* __restrict__ xcb){
  __shared__ int lohi[2];
  int g = blockIdx.x, t = threadIdx.x;
  if (t == 0){
    int lo = 0, hi = N_NODESC;
    while (lo < hi){ int mid = (lo+hi) >> 1; if (batch[mid] < g) lo = mid+1; else hi = mid; }
    lohi[0] = lo;
    int lo2 = lo; hi = N_NODESC;
    while (lo2 < hi){ int mid = (lo2+hi) >> 1; if (batch[mid] < g+1) lo2 = mid+1; else hi = mid; }
    lohi[1] = lo2;
  }
  __syncthreads();
  int lo = lohi[0], hi = lohi[1];
  float sum = 0.f, mx = 0.f;
  for (int n = lo; n < hi; n++){
    float v = h2[(size_t)n*OUT2C + t];
    sum += v * wnode[n];
    mx = fmaxf(mx, v);
  }
  xcb[(size_t)g*512 + t] = f2bf(sum);
  xcb[(size_t)g*512 + 128 + t] = f2bf(mx);
}

__global__ void k_final(const ushort_t* __restrict__ f2b, const float* __restrict__ W_out,
                        const float* __restrict__ b_out, float* __restrict__ out){
  int g = blockIdx.x*4 + (threadIdx.x >> 6);
  int l = threadIdx.x & 63;
  if (g >= N_GRAPHSC) return;
  float s = 0.f;
  #pragma unroll
  for (int k = 0; k < 4; k++) s += bf2f(f2b[(size_t)g*256 + l + 64*k]) * W_out[l + 64*k];
  #pragma unroll
  for (int off = 32; off; off >>= 1) s += __shfl_xor(s, off);
  if (l == 0) out[g] = s + b_out[0];
}

extern "C" void kernel_launch(void* const* d_in, const int* in_sizes, int n_in,
                              void* d_out, int out_size, void* d_ws, size_t ws_size,
                              hipStream_t stream) {
  const float* x      = (const float*)d_in[0];
  const int*   ei     = (const int*)d_in[1];
  const int*   batch  = (const int*)d_in[2];
  const float* target = (const float*)d_in[3];
  const float* W1     = (const float*)d_in[4];
  const float* a_src1 = (const float*)d_in[5];
  const float* a_dst1 = (const float*)d_in[6];
  const float* b1     = (const float*)d_in[7];
  const float* W2     = (const float*)d_in[8];
  const float* a_src2 = (const float*)d_in[9];
  const float* a_dst2 = (const float*)d_in[10];
  const float* b2     = (const float*)d_in[11];
  const float* w_gate = (const float*)d_in[12];
  const float* b_gate = (const float*)d_in[13];
  const float* W_xt   = (const float*)d_in[14];
  const float* b_xt   = (const float*)d_in[15];
  const float* W_fc1  = (const float*)d_in[16];
  const float* b_fc1  = (const float*)d_in[17];
  const float* W_fc2  = (const float*)d_in[18];
  const float* b_fc2  = (const float*)d_in[19];
  const float* W_out  = (const float*)d_in[20];
  const float* b_out  = (const float*)d_in[21];
  float* out = (float*)d_out;

  // ---- adaptive chunking so the carve fits ws_size (same thresholds as R4) --
  const size_t MB = (size_t)1 << 20;
  int C;
  if      (ws_size >= 410*MB) C = 1;
  else if (ws_size >= 245*MB) C = 2;
  else if (ws_size >= 165*MB) C = 4;
  else                        C = 8;
  const int R = N_NODESC / C;

  char* p = (char*)d_ws;
  auto carve = [&](size_t bytes) -> char* {
    char* r = p; p += (bytes + 255) & ~(size_t)255; return r;
  };
  int*   deg    = (int*)  carve((size_t)N_NODESC*4);
  int*   rowptr = (int*)  carve((size_t)(N_NODESC+1)*4);
  int*   cnt    = (int*)  carve((size_t)N_NODESC*4);
  int*   esrc   = (int*)  carve((size_t)E_TOTC*4);
  int*   bsum   = (int*)  carve(128*4);
  float* Wa1    = (float*)carve((size_t)F_INC*20*4);
  float* att1   = (float*)carve((size_t)N_NODESC*20*4);
  float* stat1  = (float*)carve((size_t)N_NODESC*20*4);
  float* att2   = (float*)carve((size_t)N_NODESC*2*4);
  float* stat2  = (float*)carve((size_t)N_NODESC*2*4);
  float* wnode  = (float*)carve((size_t)N_NODESC*4);
  ushort_t* W1t   = (ushort_t*)carve((size_t)HEADS1C*80*96*2);
  ushort_t* W2t   = (ushort_t*)carve((size_t)OUT2C*800*2);
  ushort_t* Wxtt  = (ushort_t*)carve((size_t)256*1280*2);
  ushort_t* Wfc1t = (ushort_t*)carve((size_t)1024*512*2);
  ushort_t* Wfc2t = (ushort_t*)carve((size_t)256*1024*2);
  ushort_t* tb    = (ushort_t*)carve((size_t)N_GRAPHSC*1280*2);
  ushort_t* h2pre = (ushort_t*)carve((size_t)N_NODESC*OUT2C*2);
  ushort_t* xcb   = (ushort_t*)carve((size_t)N_GRAPHSC*512*2);
  ushort_t* f1b   = (ushort_t*)carve((size_t)N_GRAPHSC*1024*2);
  ushort_t* f2b   = (ushort_t*)carve((size_t)N_GRAPHSC*256*2);
  size_t big_bytes = (size_t)R*F1C*2*2 + 4096;          // zc + h1c (bf16) + overread slack
  size_t h2_bytes  = (size_t)N_NODESC*OUT2C*4;          // h2 (fp32)
  char*  BIG = carve(big_bytes > h2_bytes ? big_bytes : h2_bytes);
  ushort_t* zc  = (ushort_t*)BIG;
  ushort_t* h1c = zc + (size_t)R*F1C;
  float* h2 = (float*)BIG;   // overlays zc/h1c AFTER layer-1/2 GEMMs are done

  hipMemsetAsync(deg, 0, (size_t)N_NODESC*4, stream);
  hipMemsetAsync(cnt, 0, (size_t)N_NODESC*4, stream);

  // CSR by destination (self-loops appended)
  k_deg<<<(E_TOTC+255)/256, 256, 0, stream>>>(ei, deg);
  int nb = (N_NODESC + 1023)/1024;
  k_scan1<<<nb, 1024, 0, stream>>>(deg, rowptr, bsum);
  k_scan2<<<1, 64, 0, stream>>>(bsum, rowptr, nb);
  k_scan3<<<nb, 1024, 0, stream>>>(rowptr, bsum);
  k_scatter<<<(E_TOTC+255)/256, 256, 0, stream>>>(ei, rowptr, cnt, esrc);

  // weight prep (bf16 transposed, zero-padded) + target cast
  k_prepW1<<<(HEADS1C*80*96+255)/256, 256, 0, stream>>>(W1, W1t);
  k_prepWt<<<(OUT2C*800+255)/256, 256, 0, stream>>>(W2, W2t, F1C, OUT2C, 800);
  k_prepWt<<<(256*1280+255)/256, 256, 0, stream>>>(W_xt, Wxtt, 1280, 256, 1280);
  k_prepWt<<<(1024*512+255)/256, 256, 0, stream>>>(W_fc1, Wfc1t, 512, 1024, 512);
  k_prepWt<<<(256*1024+255)/256, 256, 0, stream>>>(W_fc2, Wfc2t, 1024, 256, 1024);
  k_cast_bf<<<((N_GRAPHSC*1280)+255)/256, 256, 0, stream>>>(target, tb, N_GRAPHSC*1280);

  // layer-1 attention logits via folded weights
  k_wa1<<<(F_INC*20+255)/256, 256, 0, stream>>>(W1, a_src1, a_dst1, Wa1);
  k_att1<<<(N_NODESC*20+255)/256, 256, 0, stream>>>(x, Wa1, att1);
  k_stats1<<<(N_NODESC*HEADS1C+255)/256, 256, 0, stream>>>(att1, rowptr, esrc, stat1);

  // layer-1 (chunked): agg -> zc; MFMA per-head GEMM+b1+elu -> h1c; h1c@W2 -> h2pre
  for (int c = 0; c < C; c++){
    int base = c*R;
    k_agg1<<<R, 64, 0, stream>>>(x, att1, stat1, rowptr, esrc, zc, base);
    // K = 78 -> KB=96, KVAL=14 (cols 64..77 valid in last tile)
    mfma_gemm<80,5,96,14,2,true><<<dim3((R+63)/64, 1, HEADS1C), 256, 0, stream>>>(
        zc, W1t, b1, h1c, R, D1C, F1C, F1C,
        /*zsA*/D1C, /*zsBt*/80*96, /*zsC*/D1C, /*zsBias*/D1C);
    // K = 780 -> KB=800, KVAL=12 (cols 768..779 valid in last tile)
    mfma_gemm<128,8,800,12,0,false><<<dim3((R+63)/64, 1, 1), 256, 0, stream>>>(
        h1c, W2t, nullptr, h2pre + (size_t)base*OUT2C, R, OUT2C, F1C, OUT2C,
        0, 0, 0, 0);
  }

  // layer-2 attention + aggregation (h2 overlays the dead zc/h1c region)
  k_att2<<<(N_NODESC+3)/4, 256, 0, stream>>>(h2pre, a_src2, a_dst2, att2);
  k_stats2<<<(N_NODESC+255)/256, 256, 0, stream>>>(att2, rowptr, esrc, stat2);
  k_agg2<<<(N_NODESC+3)/4, 256, 0, stream>>>(h2pre, att2, stat2, rowptr, esrc,
                                             b2, w_gate, b_gate, h2, wnode);

  // readout (bf16) + MLP head via MFMA (K multiples of 32 -> KVAL=32, no masks)
  k_readout<<<N_GRAPHSC, 128, 0, stream>>>(h2, wnode, batch, xcb);
  mfma_gemm<128,8,1280,32,0,true><<<dim3(N_GRAPHSC/64, 256/128, 1), 256, 0, stream>>>(
      tb, Wxtt, b_xt, xcb + 256, N_GRAPHSC, 256, 1280, 512, 0,0,0,0);
  mfma_gemm<128,8,512,32,1,true><<<dim3(N_GRAPHSC/64, 1024/128, 1), 256, 0, stream>>>(
      xcb, Wfc1t, b_fc1, f1b, N_GRAPHSC, 1024, 512, 1024, 0,0,0,0);
  mfma_gemm<128,8,1024,32,1,true><<<dim3(N_GRAPHSC/64, 256/128, 1), 256, 0, stream>>>(
      f1b, Wfc2t, b_fc2, f2b, N_GRAPHSC, 256, 1024, 256, 0,0,0,0);
  k_final<<<(N_GRAPHSC+3)/4, 256, 0, stream>>>(f2b, W_out, b_out, out);
}